// Round 8
// baseline (621.963 us; speedup 1.0000x reference)
//
#include <hip/hip_runtime.h>
#include <hip/hip_fp16.h>

#define NN 50000
#define NE 800000
#define D 128
#define NB 196        // ceil(50000/256)
#define FILL_BLOCKS 1024
#define GEMM_BLOCKS 3128   // 782 * 4
#define RNG 6250      // NN / 8 (dst range per XCD)
#define ESL 6250      // edges per slice
#define NSLICE 128    // NE / ESL

typedef _Float16 half8_t __attribute__((ext_vector_type(8)));
typedef _Float16 half4_t __attribute__((ext_vector_type(4)));
typedef float f32x4 __attribute__((ext_vector_type(4)));

__device__ __forceinline__ int xcc_id() {
    // HW_REG_XCC_ID = 20, offset 0, size 32 -> imm = (31<<11) | 20
    return __builtin_amdgcn_s_getreg((31 << 11) | 20) & 7;
}

// ---------------- K0: init counters + tickets + summary slots ----------------
__global__ void k_init(int* cnt1, int* cnt2, int* tick, float* s1, float* s2) {
    int i = blockIdx.x * blockDim.x + threadIdx.x;
    int stride = gridDim.x * blockDim.x;
    for (int j = i; j < NN; j += stride) { cnt1[j] = 0; cnt2[j] = 0; }
    if (i < 16) tick[i] = 0;
    if (i < D) { s1[i] = 0.f; s2[i] = 0.f; }
}

// ---------------- K1: in-degree histogram, XCD-binned ----------------
__global__ void k_count(const int* __restrict__ dst1, const int* __restrict__ dst2,
                        int* cnt1, int* cnt2) {
    int r = blockIdx.x & 7;
    int rank = blockIdx.x >> 3;          // 0..127
    unsigned lo = r * RNG;
    int base = rank * ESL;
    for (int e = base + threadIdx.x; e < base + ESL; e += 256) {
        int d1 = dst1[e];
        if ((unsigned)(d1 - lo) < RNG) atomicAdd(&cnt1[d1], 1);
        int d2 = dst2[e];
        if ((unsigned)(d2 - lo) < RNG) atomicAdd(&cnt2[d2], 1);
    }
}

// ---------------- K2a: per-block partial sums of counts (both graphs) ----------------
__global__ void k_part(const int* __restrict__ cnt1, const int* __restrict__ cnt2,
                       int* part1, int* part2) {
    __shared__ int sm1[256], sm2[256];
    int t = threadIdx.x;
    int idx = blockIdx.x * 256 + t;
    int v1 = (idx < NN) ? cnt1[idx] : 0;
    int v2 = (idx < NN) ? cnt2[idx] : 0;
    sm1[t] = v1; sm2[t] = v2;
    __syncthreads();
    for (int off = 128; off > 0; off >>= 1) {
        if (t < off) { sm1[t] += sm1[t + off]; sm2[t] += sm2[t + off]; }
        __syncthreads();
    }
    if (t == 0) { part1[blockIdx.x] = sm1[0]; part2[blockIdx.x] = sm2[0]; }
}

// ---------------- K2b: exclusive scan of block partials (one block) ----------------
__global__ void k_scanp(int* part1, int* part2) {
    __shared__ int sm1[256], sm2[256];
    int t = threadIdx.x;
    int v1 = (t < NB) ? part1[t] : 0;
    int v2 = (t < NB) ? part2[t] : 0;
    sm1[t] = v1; sm2[t] = v2;
    __syncthreads();
    for (int off = 1; off < 256; off <<= 1) {
        int a1 = (t >= off) ? sm1[t - off] : 0;
        int a2 = (t >= off) ? sm2[t - off] : 0;
        __syncthreads();
        sm1[t] += a1; sm2[t] += a2;
        __syncthreads();
    }
    if (t < NB) { part1[t] = sm1[t] - v1; part2[t] = sm2[t] - v2; }
}

// ---------------- K2c: apply block offsets -> rp, cur, dinv ----------------
__global__ void k_apply(const int* __restrict__ cnt1, const int* __restrict__ cnt2,
                        const int* __restrict__ part1, const int* __restrict__ part2,
                        int* rp1, int* rp2, int* cur1, int* cur2,
                        float* dinv1, float* dinv2) {
    __shared__ int sm1[256], sm2[256];
    int b = blockIdx.x, t = threadIdx.x;
    int idx = b * 256 + t;
    int v1 = (idx < NN) ? cnt1[idx] : 0;
    int v2 = (idx < NN) ? cnt2[idx] : 0;
    sm1[t] = v1; sm2[t] = v2;
    __syncthreads();
    for (int off = 1; off < 256; off <<= 1) {
        int a1 = (t >= off) ? sm1[t - off] : 0;
        int a2 = (t >= off) ? sm2[t - off] : 0;
        __syncthreads();
        sm1[t] += a1; sm2[t] += a2;
        __syncthreads();
    }
    int e1 = sm1[t] - v1 + part1[b];  // exclusive prefix
    int e2 = sm2[t] - v2 + part2[b];
    if (idx < NN) {
        rp1[idx] = e1; cur1[idx] = e1; dinv1[idx] = rsqrtf((float)(v1 + 1));
        rp2[idx] = e2; cur2[idx] = e2; dinv2[idx] = rsqrtf((float)(v2 + 1));
    } else if (idx == NN) {
        rp1[NN] = e1; rp2[NN] = e2;
    }
}

// ---------------- K3+K4 merged: ticketed XCD-local CSR fill + 4 GEMMs ----------------
// Fill blocks take (graph,range) jobs matching their REAL XCD (s_getreg XCC_ID),
// graph1 job first then graph2 (phased: ~3.2MB active col set < 4MB L2), then
// steal remaining jobs for correctness under any dispatch mapping.
__launch_bounds__(256)
__global__ void k_fill_gemm(const int* __restrict__ src1, const int* __restrict__ dst1,
                            const int* __restrict__ src2, const int* __restrict__ dst2,
                            int* cur1, int* cur2, int* col1, int* col2, int* tick,
                            const float* __restrict__ x,
                            const float* __restrict__ W1, const float* __restrict__ W2,
                            const float* __restrict__ mp1, const float* __restrict__ mn1,
                            const float* __restrict__ mp2, const float* __restrict__ mn2,
                            const int* __restrict__ perm1, const int* __restrict__ perm2,
                            const float* __restrict__ dinv1, const float* __restrict__ dinv2,
                            _Float16* xwi1, _Float16* xwi2) {
    __shared__ __align__(16) _Float16 WT[128][136];
    int t = threadIdx.x;

    if (blockIdx.x < FILL_BLOCKS) {
        __shared__ int sslice;
        int myx = xcc_id();
        for (int xx = 0; xx < 8; xx++) {
            int r = (myx + xx) & 7;
            unsigned lo = r * RNG;
            for (int gj = 0; gj < 2; gj++) {
                int job = gj * 8 + r;
                const int* srcA = gj ? src2 : src1;
                const int* dstA = gj ? dst2 : dst1;
                int* curA = gj ? cur2 : cur1;
                int* colA = gj ? col2 : col1;
                while (true) {
                    if (t == 0) sslice = atomicAdd(&tick[job], 1);
                    __syncthreads();
                    int s = sslice;
                    __syncthreads();
                    if (s >= NSLICE) break;
                    int base = s * ESL;
                    for (int e = base + t; e < base + ESL; e += 256) {
                        int d = dstA[e];
                        if ((unsigned)(d - lo) < RNG) {
                            int p = atomicAdd(&curA[d], 1);
                            colA[p] = srcA[e];
                        }
                    }
                }
            }
        }
        return;
    }

    // ---- GEMM part ----
    int g = blockIdx.x - FILL_BLOCKS;      // 0..3127
    int which = g / 782;                   // 0 = pos1, 1 = neg1, 2 = pos2, 3 = neg2
    int bx = g - which * 782;
    const float* W = (which < 2) ? W1 : W2;
    const float* mask = (which == 0) ? mp1 : (which == 1) ? mn1 : (which == 2) ? mp2 : mn2;
    const int* perm = (which == 1) ? perm1 : (which == 3) ? perm2 : nullptr;
    const float* dinv = (which < 2) ? dinv1 : dinv2;
    _Float16* out = ((which < 2) ? xwi1 : xwi2) + ((which & 1) ? 128 : 0);

    for (int i = 0; i < 16; i++) {
        int idx = i * 256 + t;
        int k = idx >> 5;
        int j4 = (idx & 31) * 4;
        float4 w = ((const float4*)W)[idx];
        WT[j4 + 0][k] = (_Float16)w.x;
        WT[j4 + 1][k] = (_Float16)w.y;
        WT[j4 + 2][k] = (_Float16)w.z;
        WT[j4 + 3][k] = (_Float16)w.w;
    }
    __syncthreads();

    int wave = t >> 6;
    int lane = t & 63;
    int quad = lane >> 4;
    int m = lane & 15;
    int tile = bx * 4 + wave;
    if (tile * 16 >= NN) return;

    int row = tile * 16 + m;
    int grow = perm ? perm[row] : row;
    const float* xrow = x + (long)grow * D;
    const float* mrow = mask + (long)grow * D;

    half8_t a[4];
    for (int kk = 0; kk < 4; kk++) {
        int k0 = kk * 32 + quad * 8;
        float4 xa = *(const float4*)(xrow + k0);
        float4 xb = *(const float4*)(xrow + k0 + 4);
        float4 ma = *(const float4*)(mrow + k0);
        float4 mb = *(const float4*)(mrow + k0 + 4);
        a[kk][0] = (_Float16)(xa.x * ma.x);
        a[kk][1] = (_Float16)(xa.y * ma.y);
        a[kk][2] = (_Float16)(xa.z * ma.z);
        a[kk][3] = (_Float16)(xa.w * ma.w);
        a[kk][4] = (_Float16)(xb.x * mb.x);
        a[kk][5] = (_Float16)(xb.y * mb.y);
        a[kk][6] = (_Float16)(xb.z * mb.z);
        a[kk][7] = (_Float16)(xb.w * mb.w);
    }

    int rbase = tile * 16 + quad * 4;
    float ds0 = dinv[rbase + 0], ds1 = dinv[rbase + 1];
    float ds2 = dinv[rbase + 2], ds3 = dinv[rbase + 3];

    for (int nt = 0; nt < 8; nt++) {
        f32x4 acc = {0.f, 0.f, 0.f, 0.f};
        for (int kk = 0; kk < 4; kk++) {
            half8_t b = *(const half8_t*)(&WT[nt * 16 + m][kk * 32 + quad * 8]);
            acc = __builtin_amdgcn_mfma_f32_16x16x32_f16(a[kk], b, acc, 0, 0, 0);
        }
        int n = nt * 16 + m;
        out[(long)(rbase + 0) * 256 + n] = (_Float16)(acc[0] * ds0);
        out[(long)(rbase + 1) * 256 + n] = (_Float16)(acc[1] * ds1);
        out[(long)(rbase + 2) * 256 + n] = (_Float16)(acc[2] * ds2);
        out[(long)(rbase + 3) * 256 + n] = (_Float16)(acc[3] * ds3);
    }
}

// ---------------- K5: CSR gather, 2 edges/wave (16B per lane), shfl fold ----------------
// wave per dst node. sub = lane>>5 picks even/odd edge of a pair; q = lane&31
// covers 8 halves (16B) of the 256-half interleaved row. After the loop, odd-edge
// partials fold into even lanes via shfl_down(32); lanes 0-31 write 8 dims each.
__launch_bounds__(256)
__global__ void k_agg(const _Float16* __restrict__ xwi1, const _Float16* __restrict__ xwi2,
                      const int* __restrict__ rp1, const int* __restrict__ col1,
                      const float* __restrict__ dinv1,
                      const int* __restrict__ rp2, const int* __restrict__ col2,
                      const float* __restrict__ dinv2,
                      const float* __restrict__ b1, const float* __restrict__ b2,
                      float* out) {
    int g = blockIdx.y;
    const _Float16* xwi = g ? xwi2 : xwi1;
    const int* rp = g ? rp2 : rp1;
    const int* col = g ? col2 : col1;
    const float* dinv = g ? dinv2 : dinv1;
    const float* bias = g ? b2 : b1;
    float* pos_out = out + (g ? 12800128L : 0L);
    float* neg_out = out + (g ? 19200128L : 6400000L);

    int t = threadIdx.x;
    int wave = t >> 6, lane = t & 63;
    int i = blockIdx.x * 4 + wave;
    if (i >= NN) return;
    int sub = lane >> 5;       // 0 = even edge of pair, 1 = odd
    int q = lane & 31;
    int j8 = q * 8;            // half-index (16B) within the 256-half row

    float a0 = 0.f, a1 = 0.f, a2 = 0.f, a3 = 0.f;
    float a4 = 0.f, a5 = 0.f, a6 = 0.f, a7 = 0.f;

    // self-loop row (counted once, on sub==0)
    if (sub == 0) {
        half8_t v = *(const half8_t*)(xwi + (long)i * 256 + j8);
        a0 += (float)v[0]; a1 += (float)v[1]; a2 += (float)v[2]; a3 += (float)v[3];
        a4 += (float)v[4]; a5 += (float)v[5]; a6 += (float)v[6]; a7 += (float)v[7];
    }

    int e0 = rp[i], e1 = rp[i + 1];
    int e = e0;
    for (; e + 8 <= e1; e += 8) {
        int sA = col[e + 0 + sub], sB = col[e + 2 + sub];
        int sC = col[e + 4 + sub], sD = col[e + 6 + sub];
        half8_t vA = *(const half8_t*)(xwi + (long)sA * 256 + j8);
        half8_t vB = *(const half8_t*)(xwi + (long)sB * 256 + j8);
        half8_t vC = *(const half8_t*)(xwi + (long)sC * 256 + j8);
        half8_t vD = *(const half8_t*)(xwi + (long)sD * 256 + j8);
        a0 += (float)vA[0] + (float)vB[0] + (float)vC[0] + (float)vD[0];
        a1 += (float)vA[1] + (float)vB[1] + (float)vC[1] + (float)vD[1];
        a2 += (float)vA[2] + (float)vB[2] + (float)vC[2] + (float)vD[2];
        a3 += (float)vA[3] + (float)vB[3] + (float)vC[3] + (float)vD[3];
        a4 += (float)vA[4] + (float)vB[4] + (float)vC[4] + (float)vD[4];
        a5 += (float)vA[5] + (float)vB[5] + (float)vC[5] + (float)vD[5];
        a6 += (float)vA[6] + (float)vB[6] + (float)vC[6] + (float)vD[6];
        a7 += (float)vA[7] + (float)vB[7] + (float)vC[7] + (float)vD[7];
    }
    for (; e + 2 <= e1; e += 2) {
        int s = col[e + sub];
        half8_t v = *(const half8_t*)(xwi + (long)s * 256 + j8);
        a0 += (float)v[0]; a1 += (float)v[1]; a2 += (float)v[2]; a3 += (float)v[3];
        a4 += (float)v[4]; a5 += (float)v[5]; a6 += (float)v[6]; a7 += (float)v[7];
    }
    if (e < e1 && sub == 0) {  // odd tail edge
        int s = col[e];
        half8_t v = *(const half8_t*)(xwi + (long)s * 256 + j8);
        a0 += (float)v[0]; a1 += (float)v[1]; a2 += (float)v[2]; a3 += (float)v[3];
        a4 += (float)v[4]; a5 += (float)v[5]; a6 += (float)v[6]; a7 += (float)v[7];
    }

    // fold odd-edge partials into lanes 0-31
    a0 += __shfl_down(a0, 32); a1 += __shfl_down(a1, 32);
    a2 += __shfl_down(a2, 32); a3 += __shfl_down(a3, 32);
    a4 += __shfl_down(a4, 32); a5 += __shfl_down(a5, 32);
    a6 += __shfl_down(a6, 32); a7 += __shfl_down(a7, 32);

    if (sub == 0) {
        float di = dinv[i];
        int jj = (q < 16) ? j8 : (j8 - 128);   // dim index within D
        f32x4 bv0 = *(const f32x4*)(bias + jj);
        f32x4 bv1 = *(const f32x4*)(bias + jj + 4);
        f32x4 o0, o1;
        o0[0] = fmaxf(0.f, di * a0 + bv0[0]);
        o0[1] = fmaxf(0.f, di * a1 + bv0[1]);
        o0[2] = fmaxf(0.f, di * a2 + bv0[2]);
        o0[3] = fmaxf(0.f, di * a3 + bv0[3]);
        o1[0] = fmaxf(0.f, di * a4 + bv1[0]);
        o1[1] = fmaxf(0.f, di * a5 + bv1[1]);
        o1[2] = fmaxf(0.f, di * a6 + bv1[2]);
        o1[3] = fmaxf(0.f, di * a7 + bv1[3]);
        float* dst = ((q < 16) ? pos_out : neg_out) + (long)i * D + jj;
        __builtin_nontemporal_store(o0, (f32x4*)dst);
        __builtin_nontemporal_store(o1, (f32x4*)(dst + 4));
    }
}

// ---------------- K6: summary mean over pos_h ----------------
__launch_bounds__(256)
__global__ void k_sum(const float* __restrict__ pos1, const float* __restrict__ pos2,
                      float* s1, float* s2) {
    int g = blockIdx.y;
    const float* pos = g ? pos2 : pos1;
    float* s = g ? s2 : s1;
    int t = threadIdx.x;
    int rg = t >> 5;
    int j = (t & 31) * 4;
    float4 acc = {0.f, 0.f, 0.f, 0.f};
    for (int i = blockIdx.x * 8 + rg; i < NN; i += gridDim.x * 8) {
        float4 v = *(const float4*)(pos + (long)i * D + j);
        acc.x += v.x; acc.y += v.y; acc.z += v.z; acc.w += v.w;
    }
    __shared__ float sm[8][128];
    sm[rg][j + 0] = acc.x;
    sm[rg][j + 1] = acc.y;
    sm[rg][j + 2] = acc.z;
    sm[rg][j + 3] = acc.w;
    __syncthreads();
    if (t < 128) {
        float v = 0.f;
        for (int r = 0; r < 8; r++) v += sm[r][t];
        atomicAdd(&s[t], v * (1.0f / NN));
    }
}

extern "C" void kernel_launch(void* const* d_in, const int* in_sizes, int n_in,
                              void* d_out, int out_size, void* d_ws, size_t ws_size,
                              hipStream_t stream) {
    const float* x   = (const float*)d_in[0];
    const float* W1  = (const float*)d_in[1];
    const float* b1  = (const float*)d_in[2];
    const float* W2  = (const float*)d_in[3];
    const float* b2  = (const float*)d_in[4];
    const float* mp1 = (const float*)d_in[5];
    const float* mn1 = (const float*)d_in[6];
    const float* mp2 = (const float*)d_in[7];
    const float* mn2 = (const float*)d_in[8];
    const int* e1 = (const int*)d_in[9];
    const int* e2 = (const int*)d_in[10];
    const int* perm1 = (const int*)d_in[11];
    const int* perm2 = (const int*)d_in[12];
    const int* src1 = e1;       const int* dst1 = e1 + NE;
    const int* src2 = e2;       const int* dst2 = e2 + NE;
    float* out = (float*)d_out;

    // workspace carve
    char* w = (char*)d_ws;
    _Float16* xwi1 = (_Float16*)w; w += (size_t)NN * 256 * 2;  // 25.6 MB interleaved
    _Float16* xwi2 = (_Float16*)w; w += (size_t)NN * 256 * 2;
    int* cnt1 = (int*)w;  w += (size_t)NN * 4;
    int* cnt2 = (int*)w;  w += (size_t)NN * 4;
    int* cur1 = (int*)w;  w += (size_t)NN * 4;
    int* cur2 = (int*)w;  w += (size_t)NN * 4;
    int* rp1 = (int*)w;   w += (size_t)(NN + 4) * 4;
    int* rp2 = (int*)w;   w += (size_t)(NN + 4) * 4;
    int* col1 = (int*)w;  w += (size_t)NE * 4;
    int* col2 = (int*)w;  w += (size_t)NE * 4;
    float* dinv1 = (float*)w; w += (size_t)NN * 4;
    float* dinv2 = (float*)w; w += (size_t)NN * 4;
    int* part1 = (int*)w; w += (size_t)256 * 4;
    int* part2 = (int*)w; w += (size_t)256 * 4;
    int* tick  = (int*)w; w += (size_t)16 * 4;

    float* s1 = out + 12800000L;
    float* s2 = out + 25600128L;
    const float* pos1 = out;
    const float* pos2 = out + 12800128L;

    k_init<<<dim3(256), 256, 0, stream>>>(cnt1, cnt2, tick, s1, s2);
    k_count<<<dim3(1024), 256, 0, stream>>>(dst1, dst2, cnt1, cnt2);
    k_part<<<dim3(NB), 256, 0, stream>>>(cnt1, cnt2, part1, part2);
    k_scanp<<<dim3(1), 256, 0, stream>>>(part1, part2);
    k_apply<<<dim3(NB), 256, 0, stream>>>(cnt1, cnt2, part1, part2,
                                          rp1, rp2, cur1, cur2, dinv1, dinv2);
    k_fill_gemm<<<dim3(FILL_BLOCKS + GEMM_BLOCKS), 256, 0, stream>>>(
        src1, dst1, src2, dst2, cur1, cur2, col1, col2, tick,
        x, W1, W2, mp1, mn1, mp2, mn2, perm1, perm2, dinv1, dinv2, xwi1, xwi2);
    k_agg<<<dim3(12500, 2), 256, 0, stream>>>(xwi1, xwi2,
                                              rp1, col1, dinv1, rp2, col2, dinv2,
                                              b1, b2, out);
    k_sum<<<dim3(128, 2), 256, 0, stream>>>(pos1, pos2, s1, s2);
}